// Round 9
// baseline (291.323 us; speedup 1.0000x reference)
//
#include <hip/hip_runtime.h>
#include <hip/hip_fp16.h>

// StaticGNN: 2-layer GCN. N=50000, E=800000, D=128, fp32 in/out.
// out = relu( D^{-1/2}(A+I)D^{-1/2} (X W_l) + b_l ), x2.
// H fp16; CSR recs int2{src,coef}, band-sorted per node (src>>13).
// R23 = TEMPORAL BAND SWEEP. R22 lesson: per-list band sort is useless when
// the band loop is inside the node loop (every node touches every band ->
// working set = all of H). R23 hoists the band loop OUTSIDE: quarter-wave
// owns 2 nodes, sweeps 8 src-bands; all ~768 resident blocks sweep in
// near-lockstep -> instantaneous H window = 2MB band -> per-XCD L2 holds it
// -> 16x row reuse becomes L2 hits (200cy) instead of L3 hits (500cy),
// lifting the per-CU L1-miss-throughput wall (~MSHR/latency) by ~2.5x.
// base8 re-laid node-major [N][9] ([8]=deg) so band bounds are 2 uniform
// loads per band. Summation order per node unchanged -> absmax identical.
// 7 dispatches: memset, count, scanA+cvtw, scanC2, gemmfill, aggemm, agg_out.

#define D 128
#define WP 136   // LDS pitch (halves) for W^T tile
#define YP 136   // LDS pitch (halves) for y-tile in aggemm
#define NB_SCAN 196     // ceil(50000/256)

typedef _Float16 half8 __attribute__((ext_vector_type(8)));
typedef float floatx4 __attribute__((ext_vector_type(4)));

// ---------------- setup kernels ----------------

// deg8[8][n] zeroed by memset. Replica c = SRC BAND (s>>13, 0..6 for
// N=50000; band 7 empty). rank = within-(dst,band) arrival rank.
__global__ void count_kernel(const int* __restrict__ src,
                             const int* __restrict__ dst, int* deg8,
                             int* __restrict__ rank, int e, int n) {
    int i = blockIdx.x * blockDim.x + threadIdx.x;
    if (i < e) {
        int c = (src[i] >> 13) * n;
        rank[i] = atomicAdd(&deg8[c + dst[i]], 1);
    }
}

// scanA: per-node band-exclusive bases -> base9[v*9+c] (c=0..7), [8]=deg.
// Block sums -> partial. cvtw (W fp32 -> W^T fp16) fused tail.
__global__ __launch_bounds__(256) void scanA_cvtw_kernel(const int* __restrict__ deg8,
                                                         int* __restrict__ degT,
                                                         int* __restrict__ base9,
                                                         int* __restrict__ partial,
                                                         int n, int nbs,
                                                         const float* __restrict__ W,
                                                         __half* __restrict__ WhT) {
    __shared__ int red[4];
    int tid = threadIdx.x;
    int bid = blockIdx.x;
    if (bid < nbs) {
        int i = bid * 256 + tid;
        int tot = 0;
        if (i < n) {
            int run = 0;
#pragma unroll
            for (int c = 0; c < 8; ++c) {
                base9[(size_t)i * 9 + c] = run;
                run += deg8[c * n + i];
            }
            base9[(size_t)i * 9 + 8] = run;
            degT[i] = run;
            tot = run;
        }
        for (int off = 32; off > 0; off >>= 1) tot += __shfl_down(tot, off, 64);
        if ((tid & 63) == 0) red[tid >> 6] = tot;
        __syncthreads();
        if (tid == 0) partial[bid] = red[0] + red[1] + red[2] + red[3];
    } else {
        // W[l][k][f] -> WhT[l][f][k]; 128 blocks x 256 threads = 32768 elems
        int id = (bid - nbs) * 256 + tid;
        int l = id >> 14;
        int rem = id & 16383;
        int f = rem >> 7;
        int k = rem & 127;
        WhT[id] = __float2half(W[l * 16384 + k * 128 + f]);
    }
}

// scanC2: scanB folded in -- every block locally scans the 196 partials,
// then does its in-block node scan. Writes row_ptr + dinv.
__global__ __launch_bounds__(256) void scanC2_kernel(const int* __restrict__ degT,
                                                     const int* __restrict__ partial,
                                                     int* __restrict__ row_ptr,
                                                     float* __restrict__ dinv, int n) {
    __shared__ int sc[256];
    __shared__ int scb[256];
    int tid = threadIdx.x;
    int bid = blockIdx.x;
    int p = (tid < NB_SCAN) ? partial[tid] : 0;
    scb[tid] = p;
    __syncthreads();
    for (int off = 1; off < 256; off <<= 1) {
        int v = (tid >= off) ? scb[tid - off] : 0;
        __syncthreads();
        scb[tid] += v;
        __syncthreads();
    }
    int i = bid * 256 + tid;
    int c = (i < n) ? degT[i] : 0;
    sc[tid] = c;
    __syncthreads();
    for (int off = 1; off < 256; off <<= 1) {
        int v = (tid >= off) ? sc[tid - off] : 0;
        __syncthreads();
        sc[tid] += v;
        __syncthreads();
    }
    if (i < n) {
        int base = ((bid == 0) ? 0 : scb[bid - 1]) + sc[tid] - c;
        row_ptr[i] = base;
        dinv[i] = rsqrtf((float)(c + 1));
    }
    if (bid == 0 && tid == 0) row_ptr[n] = scb[NB_SCAN - 1];
}

// ---------------- shared device bodies ----------------

__device__ inline void gemm_body(int bid, int tid,
                                 const float* __restrict__ Xf,
                                 const __half* __restrict__ WhT,
                                 __half* __restrict__ Hh, int n,
                                 _Float16* wlds) {
#pragma unroll
    for (int q = 0; q < 8; ++q) {
        int idx = tid + q * 256;        // 0..2047, each = 8 halves
        int row = idx >> 4;
        int col8 = (idx & 15) * 8;
        const uint2* gsrc = (const uint2*)(WhT + row * 128 + col8);
        uint2 a = gsrc[0];
        uint2 b = gsrc[1];
        uint2* ldst = (uint2*)(wlds + row * WP + col8);
        ldst[0] = a;
        ldst[1] = b;
    }
    __syncthreads();

    const int wave = tid >> 6;
    const int lane = tid & 63;
    const int m = lane & 15;
    const int quad = lane >> 4;

    const int node = bid * 64 + wave * 16 + m;
    const int node_ld = node < n ? node : (n - 1);

    half8 bfr[4];
#pragma unroll
    for (int k = 0; k < 4; ++k) {
        const float4* p = (const float4*)(Xf + (size_t)node_ld * 128 + k * 32 + quad * 8);
        float4 lo = p[0];
        float4 hi = p[1];
        half8 h;
        h[0] = (_Float16)lo.x; h[1] = (_Float16)lo.y;
        h[2] = (_Float16)lo.z; h[3] = (_Float16)lo.w;
        h[4] = (_Float16)hi.x; h[5] = (_Float16)hi.y;
        h[6] = (_Float16)hi.z; h[7] = (_Float16)hi.w;
        bfr[k] = h;
    }

    floatx4 acc[8];
#pragma unroll
    for (int f = 0; f < 8; ++f) acc[f] = (floatx4){0.f, 0.f, 0.f, 0.f};

#pragma unroll
    for (int f = 0; f < 8; ++f) {
#pragma unroll
        for (int k = 0; k < 4; ++k) {
            half8 a = *(const half8*)(wlds + (f * 16 + m) * WP + k * 32 + quad * 8);
            acc[f] = __builtin_amdgcn_mfma_f32_16x16x32_f16(a, bfr[k], acc[f], 0, 0, 0);
        }
    }

    if (node < n) {
#pragma unroll
        for (int f = 0; f < 8; ++f) {
            __half2 p0 = __floats2half2_rn(acc[f][0], acc[f][1]);
            __half2 p1 = __floats2half2_rn(acc[f][2], acc[f][3]);
            uint2 pk;
            pk.x = *(unsigned int*)&p0;
            pk.y = *(unsigned int*)&p1;
            *(uint2*)(Hh + (size_t)node * 128 + f * 16 + quad * 4) = pk;
        }
    }
}

__device__ inline void fill_body(int i,
                                 const int* __restrict__ src,
                                 const int* __restrict__ dst,
                                 const int* __restrict__ rank,
                                 const int* __restrict__ row_ptr,
                                 const int* __restrict__ base9,
                                 const float* __restrict__ dinv,
                                 int2* __restrict__ recs, int e, int n) {
    if (i < e) {
        int d = dst[i];
        int s = src[i];
        int c = s >> 13;        // src band -- must match count_kernel
        int pos = row_ptr[d] + base9[(size_t)d * 9 + c] + rank[i];
        int2 rec;
        rec.x = s;
        rec.y = __float_as_int(dinv[s] * dinv[d]);
        recs[pos] = rec;
    }
}

// ---------------- fused layer-0 GEMM + CSR fill (measured win: overlap) ----------------

__global__ __launch_bounds__(256) void gemmfill_kernel(const float* __restrict__ Xf,
                                                       const __half* __restrict__ WhT,
                                                       __half* __restrict__ Hh, int n, int nbg,
                                                       const int* __restrict__ src,
                                                       const int* __restrict__ dst,
                                                       const int* __restrict__ rank,
                                                       const int* __restrict__ row_ptr,
                                                       const int* __restrict__ base9,
                                                       const float* __restrict__ dinv,
                                                       int2* __restrict__ recs, int e) {
    __shared__ _Float16 wlds[128 * WP];
    int bid = blockIdx.x;
    int tid = threadIdx.x;
    if (bid < nbg) {
        gemm_body(bid, tid, Xf, WhT, Hh, n, wlds);
    } else {
        fill_body((bid - nbg) * 256 + tid, src, dst, rank, row_ptr, base9, dinv, recs, e, n);
    }
}

// ---------------- Aggregation core (R23: band-phased pair walk) ----------------

__device__ inline void unpack8(uint4 u, float* f) {
    union { unsigned int x; __half2 h; } a, b, c, d;
    a.x = u.x; b.x = u.y; c.x = u.z; d.x = u.w;
    float2 f0 = __half22float2(a.h);
    float2 f1 = __half22float2(b.h);
    float2 f2 = __half22float2(c.h);
    float2 f3 = __half22float2(d.h);
    f[0] = f0.x; f[1] = f0.y; f[2] = f1.x; f[3] = f1.y;
    f[4] = f2.x; f[5] = f2.y; f[6] = f3.x; f[7] = f3.y;
}

// Quarter-wave owns nodes v0, v1 (either may be >= n). Outer loop over the
// 8 src-bands; per band, both nodes' band-local edge ranges are walked with
// 4-deep predicated batches each (8 gathers in flight per quarter).
// Band bounds: [rp + b9[c], rp + b9[c+1]), b9[8] = deg. Lane fl owns
// features [fl*8, fl*8+8); acc = complete row sums (no cross-lane reduce).
__device__ inline void agg_pair_banded(int v0, int v1, int fl, int n,
                                       const uint4* __restrict__ H16,
                                       const int2* __restrict__ recs,
                                       const int* __restrict__ row_ptr,
                                       const int* __restrict__ base9,
                                       const float* __restrict__ dinv,
                                       float* a0, float* a1) {
    const bool k0 = v0 < n, k1 = v1 < n;
    const int rp0 = k0 ? row_ptr[v0] : 0;
    const int rp1 = k1 ? row_ptr[v1] : 0;
    const int* b0p = base9 + (size_t)(k0 ? v0 : 0) * 9;
    const int* b1p = base9 + (size_t)(k1 ? v1 : 0) * 9;

    if (k0) {
        float di = dinv[v0];
        float sc = di * di;
        uint4 hv = H16[(size_t)v0 * 16 + fl];
        float f[8]; unpack8(hv, f);
#pragma unroll
        for (int t = 0; t < 8; ++t) a0[t] = f[t] * sc;
    } else {
#pragma unroll
        for (int t = 0; t < 8; ++t) a0[t] = 0.f;
    }
    if (k1) {
        float di = dinv[v1];
        float sc = di * di;
        uint4 hv = H16[(size_t)v1 * 16 + fl];
        float f[8]; unpack8(hv, f);
#pragma unroll
        for (int t = 0; t < 8; ++t) a1[t] = f[t] * sc;
    } else {
#pragma unroll
        for (int t = 0; t < 8; ++t) a1[t] = 0.f;
    }

#pragma unroll 1
    for (int c = 0; c < 8; ++c) {
        int s0 = 0, e0 = 0, s1 = 0, e1 = 0;
        if (k0) { s0 = rp0 + b0p[c]; e0 = rp0 + b0p[c + 1]; }
        if (k1) { s1 = rp1 + b1p[c]; e1 = rp1 + b1p[c + 1]; }
        while (s0 < e0 || s1 < e1) {
            int2 r0[4], r1[4]; uint4 h0[4], h1[4];
            bool c0[4], c1[4];
#pragma unroll
            for (int j = 0; j < 4; ++j) {
                c0[j] = (s0 + j) < e0;
                if (c0[j]) r0[j] = recs[s0 + j];
            }
#pragma unroll
            for (int j = 0; j < 4; ++j) {
                c1[j] = (s1 + j) < e1;
                if (c1[j]) r1[j] = recs[s1 + j];
            }
#pragma unroll
            for (int j = 0; j < 4; ++j) {
                if (c0[j]) h0[j] = H16[(size_t)r0[j].x * 16 + fl];
            }
#pragma unroll
            for (int j = 0; j < 4; ++j) {
                if (c1[j]) h1[j] = H16[(size_t)r1[j].x * 16 + fl];
            }
#pragma unroll
            for (int j = 0; j < 4; ++j) {
                if (c0[j]) {
                    float cf = __int_as_float(r0[j].y);
                    float f[8]; unpack8(h0[j], f);
#pragma unroll
                    for (int t = 0; t < 8; ++t) a0[t] = fmaf(f[t], cf, a0[t]);
                }
            }
#pragma unroll
            for (int j = 0; j < 4; ++j) {
                if (c1[j]) {
                    float cf = __int_as_float(r1[j].y);
                    float f[8]; unpack8(h1[j], f);
#pragma unroll
                    for (int t = 0; t < 8; ++t) a1[t] = fmaf(f[t], cf, a1[t]);
                }
            }
            s0 += 4; s1 += 4;
        }
    }
}

// ---------------- fused agg(layer0) + GEMM(layer1), 64-node tile ----------------
// Block g: 32 quarters x 2 nodes = 64 nodes, band-swept into LDS y-tile,
// block-local barrier, then 64x128 @ W2 MFMA (R17-verified phase 2).
// Output -> H2 (NOT H: other blocks still gather from H).
__global__ __launch_bounds__(512, 3) void aggemm_kernel(
    const __half* __restrict__ H,
    const int2* __restrict__ recs,
    const int* __restrict__ row_ptr,
    const int* __restrict__ base9,
    const float* __restrict__ dinv,
    const float* __restrict__ bias,       // layer-0 bias
    const __half* __restrict__ WhT2,      // layer-1 W^T
    __half* __restrict__ H2, int n) {
    __shared__ _Float16 yt[64 * YP];
    const int tid = threadIdx.x;
    const int wave = tid >> 6;
    const int lane = tid & 63;
    const int qw = lane >> 4;
    const int fl = lane & 15;
    const int g = blockIdx.x;
    const uint4* H16 = (const uint4*)H;

    // ---- phase 1: band-phased pair walk into y-tile ----
    {
        const int q = wave * 4 + qw;     // quarter id 0..31
        const int r0 = q * 2;            // local rows
        const int v0 = g * 64 + r0;
        const int v1 = v0 + 1;
        float a0[8], a1[8];
        agg_pair_banded(v0, v1, fl, n, H16, recs, row_ptr, base9, dinv, a0, a1);

        const float4* B4 = (const float4*)bias;
        float4 bb0 = B4[fl * 2];
        float4 bb1 = B4[fl * 2 + 1];
        {
            __half2 p0 = __floats2half2_rn(fmaxf(a0[0] + bb0.x, 0.f), fmaxf(a0[1] + bb0.y, 0.f));
            __half2 p1 = __floats2half2_rn(fmaxf(a0[2] + bb0.z, 0.f), fmaxf(a0[3] + bb0.w, 0.f));
            __half2 p2 = __floats2half2_rn(fmaxf(a0[4] + bb1.x, 0.f), fmaxf(a0[5] + bb1.y, 0.f));
            __half2 p3 = __floats2half2_rn(fmaxf(a0[6] + bb1.z, 0.f), fmaxf(a0[7] + bb1.w, 0.f));
            uint4 pk;
            pk.x = *(unsigned int*)&p0;
            pk.y = *(unsigned int*)&p1;
            pk.z = *(unsigned int*)&p2;
            pk.w = *(unsigned int*)&p3;
            *(uint4*)&yt[r0 * YP + fl * 8] = pk;
        }
        {
            __half2 p0 = __floats2half2_rn(fmaxf(a1[0] + bb0.x, 0.f), fmaxf(a1[1] + bb0.y, 0.f));
            __half2 p1 = __floats2half2_rn(fmaxf(a1[2] + bb0.z, 0.f), fmaxf(a1[3] + bb0.w, 0.f));
            __half2 p2 = __floats2half2_rn(fmaxf(a1[4] + bb1.x, 0.f), fmaxf(a1[5] + bb1.y, 0.f));
            __half2 p3 = __floats2half2_rn(fmaxf(a1[6] + bb1.z, 0.f), fmaxf(a1[7] + bb1.w, 0.f));
            uint4 pk;
            pk.x = *(unsigned int*)&p0;
            pk.y = *(unsigned int*)&p1;
            pk.z = *(unsigned int*)&p2;
            pk.w = *(unsigned int*)&p3;
            *(uint4*)&yt[(r0 + 1) * YP + fl * 8] = pk;
        }
        // rows for v >= n are written as zeros by agg_pair_banded + relu(0+b)?
        // NOTE: for v>=n, a=0 but bias would leak -- mask: overwrite with 0.
        if (v0 >= n) { uint4 z = make_uint4(0, 0, 0, 0); *(uint4*)&yt[r0 * YP + fl * 8] = z; }
        if (v1 >= n) { uint4 z = make_uint4(0, 0, 0, 0); *(uint4*)&yt[(r0 + 1) * YP + fl * 8] = z; }
    }
    __syncthreads();

    // ---- phase 2: GEMM 64x128 @ W2 -> H2 (R17-verified mapping) ----
    const int mg = wave & 3;             // node-group (16 nodes)
    const int fh = wave >> 2;            // feature half (4 f-blocks)
    const int node = g * 64 + mg * 16 + fl;

    half8 bfr[4];
#pragma unroll
    for (int k = 0; k < 4; ++k)
        bfr[k] = *(const half8*)&yt[(mg * 16 + fl) * YP + k * 32 + qw * 8];

#pragma unroll
    for (int fb = 0; fb < 4; ++fb) {
        int f = fh * 4 + fb;
        floatx4 a4 = (floatx4){0.f, 0.f, 0.f, 0.f};
#pragma unroll
        for (int k = 0; k < 4; ++k) {
            half8 a = *(const half8*)(WhT2 + ((f * 16 + fl) * 128 + k * 32 + qw * 8));
            a4 = __builtin_amdgcn_mfma_f32_16x16x32_f16(a, bfr[k], a4, 0, 0, 0);
        }
        if (node < n) {
            __half2 p0 = __floats2half2_rn(a4[0], a4[1]);
            __half2 p1 = __floats2half2_rn(a4[2], a4[3]);
            uint2 pk;
            pk.x = *(unsigned int*)&p0;
            pk.y = *(unsigned int*)&p1;
            *(uint2*)(H2 + (size_t)node * 128 + f * 16 + qw * 4) = pk;
        }
    }
}

// ---------------- final agg (layer 1 -> fp32 out), band-phased ----------------
__global__ __launch_bounds__(512, 3) void agg_out_kernel(
    const __half* __restrict__ H,
    const int2* __restrict__ recs,
    const int* __restrict__ row_ptr,
    const int* __restrict__ base9,
    const float* __restrict__ dinv,
    const float* __restrict__ bias,
    float* __restrict__ YF, int n) {
    const int tid = threadIdx.x;
    const int wave = tid >> 6;
    const int lane = tid & 63;
    const int qw = lane >> 4;
    const int fl = lane & 15;
    const int q = wave * 4 + qw;
    const int v0 = blockIdx.x * 64 + q * 2;
    const int v1 = v0 + 1;
    const uint4* H16 = (const uint4*)H;

    float a0[8], a1[8];
    agg_pair_banded(v0, v1, fl, n, H16, recs, row_ptr, base9, dinv, a0, a1);

    const float4* B4 = (const float4*)bias;
    float4 bb0 = B4[fl * 2];
    float4 bb1 = B4[fl * 2 + 1];
    float4* Y4 = (float4*)YF;
    if (v0 < n) {
        Y4[(size_t)v0 * 32 + fl * 2] = make_float4(
            fmaxf(a0[0] + bb0.x, 0.f), fmaxf(a0[1] + bb0.y, 0.f),
            fmaxf(a0[2] + bb0.z, 0.f), fmaxf(a0[3] + bb0.w, 0.f));
        Y4[(size_t)v0 * 32 + fl * 2 + 1] = make_float4(
            fmaxf(a0[4] + bb1.x, 0.f), fmaxf(a0[5] + bb1.y, 0.f),
            fmaxf(a0[6] + bb1.z, 0.f), fmaxf(a0[7] + bb1.w, 0.f));
    }
    if (v1 < n) {
        Y4[(size_t)v1 * 32 + fl * 2] = make_float4(
            fmaxf(a1[0] + bb0.x, 0.f), fmaxf(a1[1] + bb0.y, 0.f),
            fmaxf(a1[2] + bb0.z, 0.f), fmaxf(a1[3] + bb0.w, 0.f));
        Y4[(size_t)v1 * 32 + fl * 2 + 1] = make_float4(
            fmaxf(a1[4] + bb1.x, 0.f), fmaxf(a1[5] + bb1.y, 0.f),
            fmaxf(a1[6] + bb1.z, 0.f), fmaxf(a1[7] + bb1.w, 0.f));
    }
}

// ---------------- launch ----------------

extern "C" void kernel_launch(void* const* d_in, const int* in_sizes, int n_in,
                              void* d_out, int out_size, void* d_ws, size_t ws_size,
                              hipStream_t stream) {
    const float* x = (const float*)d_in[0];
    const int* ei = (const int*)d_in[1];
    const float* W = (const float*)d_in[2];
    const float* b = (const float*)d_in[3];
    float* out = (float*)d_out;

    const int N = in_sizes[0] / D;       // 50000
    const int E = in_sizes[1] / 2;       // 800000

    const int* src = ei;
    const int* dst = ei + E;

    int* wsi = (int*)d_ws;
    float* wsf = (float*)d_ws;
    const size_t o_deg8 = 0;                 // 8*N ints (memset 0)
    const size_t o_degT = o_deg8 + 400000;   // N ints
    const size_t o_dinv = o_degT + 50000;    // N floats
    const size_t o_rp   = o_dinv + 50000;    // N+1 ints (pad 50016)
    const size_t o_part = o_rp + 50016;      // 256
    const size_t o_b9   = o_part + 256;      // 9*N ints node-major (pad 450048)
    const size_t o_rank = o_b9 + 450048;     // E ints
    const size_t o_rec  = o_rank + 800000;   // E int2 (region 16B-aligned)
    const size_t o_h    = o_rec + 1600000;   // N*128 halves = 3.2M words (16B-aligned)
    const size_t o_wht  = o_h + 3200000;     // 2*128*128 halves = 16384 words
    const size_t o_h2   = o_wht + 16384;     // N*128 halves (layer-1 GEMM out)

    int* deg8    = wsi + o_deg8;
    int* degT    = wsi + o_degT;
    float* dinv  = wsf + o_dinv;
    int* row_ptr = wsi + o_rp;
    int* partial = wsi + o_part;
    int* base9   = wsi + o_b9;
    int* rank    = wsi + o_rank;
    int2* recs   = (int2*)(wsi + o_rec);
    __half* h    = (__half*)(wsi + o_h);
    __half* wht  = (__half*)(wsi + o_wht);
    __half* h2   = (__half*)(wsi + o_h2);

    const int nb_e = (E + 255) / 256;           // 3125
    const int nb_s = (N + 255) / 256;           // 196
    const int nb_g = (N + 63) / 64;             // 782
    const int nb_a = (N + 63) / 64;             // 782 (64 nodes per 512-thr block)

    hipMemsetAsync(deg8, 0, (size_t)8 * 50000 * sizeof(int), stream);
    count_kernel<<<nb_e, 256, 0, stream>>>(src, dst, deg8, rank, E, N);
    scanA_cvtw_kernel<<<nb_s + 128, 256, 0, stream>>>(deg8, degT, base9, partial,
                                                      N, nb_s, W, wht);
    scanC2_kernel<<<nb_s, 256, 0, stream>>>(degT, partial, row_ptr, dinv, N);
    // fused: layer-0 GEMM (blocks [0,nb_g)) + CSR fill (blocks [nb_g,...))
    gemmfill_kernel<<<nb_g + nb_e, 256, 0, stream>>>(x, wht, h, N, nb_g,
                                                     src, dst, rank, row_ptr, base9,
                                                     dinv, recs, E);
    // fused: band-swept agg layer-0 + GEMM layer-1
    aggemm_kernel<<<nb_g, 512, 0, stream>>>(h, recs, row_ptr, base9, dinv, b,
                                            wht + 16384, h2, N);
    // band-swept final agg -> fp32 out
    agg_out_kernel<<<nb_a, 512, 0, stream>>>(h2, recs, row_ptr, base9, dinv,
                                             b + D, out, N);
}

// Round 10
// 240.624 us; speedup vs baseline: 1.2107x; 1.2107x over previous
//
#include <hip/hip_runtime.h>
#include <hip/hip_fp16.h>

// StaticGNN: 2-layer GCN. N=50000, E=800000, D=128, fp32 in/out.
// out = relu( D^{-1/2}(A+I)D^{-1/2} (X W_l) + b_l ), x2.
// H fp16; CSR recs int2{src,coef}, band-sorted per node (src>>13).
// R24 = R22 (measured best: quarter-per-node ABI-predicated agg, banded
// counting sort) + ABI 8->12 (predicated deepening; R20 showed always-issue
// batches regress, predicated ones don't change issue count) + RANK-FREE
// fill (second atomic cursor assigns slots; deletes rank array's 3.2MB
// write + 3.2MB read). R23 lesson: band-swept locality (+15% FETCH cut)
// loses to the MLP it destroys; agg L2-miss service is wall-like at
// ~1.7 TB/s across 6 structures. This round is the final latency-vs-wall
// discriminator: aggemm 43 => trips still mattered; 46-48 => roofline.
// 7 dispatches: memset, count, scanA+cvtw, scanC2, gemmfill, aggemm, agg2.

#define D 128
#define WP 136   // LDS pitch (halves) for W^T tile
#define YP 136   // LDS pitch (halves) for y-tile in aggemm
#define ABI 12   // edges in flight per quarter-wave (gather pipeline depth)
#define AGT 32   // aggemm node tile (8 waves x 4 nodes, 1 node per quarter)
#define NB_SCAN 196     // ceil(50000/256)

typedef _Float16 half8 __attribute__((ext_vector_type(8)));
typedef float floatx4 __attribute__((ext_vector_type(4)));

// ---------------- setup kernels ----------------

// deg8[8][n] zeroed by memset. Replica c = SRC BAND (s>>13, 0..6 for
// N=50000). Histogram only -- slot ranks are assigned in fill via cursor8.
__global__ void count_kernel(const int* __restrict__ src,
                             const int* __restrict__ dst, int* deg8,
                             int e, int n) {
    int i = blockIdx.x * blockDim.x + threadIdx.x;
    if (i < e) {
        int c = (src[i] >> 13) * n;
        atomicAdd(&deg8[c + dst[i]], 1);
    }
}

// scanA: per-node total degree + per-band exclusive bases; block sums -> partial.
// cvtw (W fp32 -> W^T fp16) fused as independent block-range tail.
__global__ __launch_bounds__(256) void scanA_cvtw_kernel(const int* __restrict__ deg8,
                                                         int* __restrict__ degT,
                                                         int* __restrict__ base8,
                                                         int* __restrict__ partial,
                                                         int n, int nbs,
                                                         const float* __restrict__ W,
                                                         __half* __restrict__ WhT) {
    __shared__ int red[4];
    int tid = threadIdx.x;
    int bid = blockIdx.x;
    if (bid < nbs) {
        int i = bid * 256 + tid;
        int tot = 0;
        if (i < n) {
            int run = 0;
#pragma unroll
            for (int c = 0; c < 8; ++c) {
                base8[c * n + i] = run;
                run += deg8[c * n + i];
            }
            degT[i] = run;
            tot = run;
        }
        for (int off = 32; off > 0; off >>= 1) tot += __shfl_down(tot, off, 64);
        if ((tid & 63) == 0) red[tid >> 6] = tot;
        __syncthreads();
        if (tid == 0) partial[bid] = red[0] + red[1] + red[2] + red[3];
    } else {
        // W[l][k][f] -> WhT[l][f][k]; 128 blocks x 256 threads = 32768 elems
        int id = (bid - nbs) * 256 + tid;
        int l = id >> 14;
        int rem = id & 16383;
        int f = rem >> 7;
        int k = rem & 127;
        WhT[id] = __float2half(W[l * 16384 + k * 128 + f]);
    }
}

// scanC2: scanB folded in -- every block locally scans the 196 partials,
// then does its in-block node scan. Writes row_ptr + dinv.
__global__ __launch_bounds__(256) void scanC2_kernel(const int* __restrict__ degT,
                                                     const int* __restrict__ partial,
                                                     int* __restrict__ row_ptr,
                                                     float* __restrict__ dinv, int n) {
    __shared__ int sc[256];
    __shared__ int scb[256];
    int tid = threadIdx.x;
    int bid = blockIdx.x;
    int p = (tid < NB_SCAN) ? partial[tid] : 0;
    scb[tid] = p;
    __syncthreads();
    for (int off = 1; off < 256; off <<= 1) {
        int v = (tid >= off) ? scb[tid - off] : 0;
        __syncthreads();
        scb[tid] += v;
        __syncthreads();
    }
    int i = bid * 256 + tid;
    int c = (i < n) ? degT[i] : 0;
    sc[tid] = c;
    __syncthreads();
    for (int off = 1; off < 256; off <<= 1) {
        int v = (tid >= off) ? sc[tid - off] : 0;
        __syncthreads();
        sc[tid] += v;
        __syncthreads();
    }
    if (i < n) {
        int base = ((bid == 0) ? 0 : scb[bid - 1]) + sc[tid] - c;
        row_ptr[i] = base;
        dinv[i] = rsqrtf((float)(c + 1));
    }
    if (bid == 0 && tid == 0) row_ptr[n] = scb[NB_SCAN - 1];
}

// ---------------- shared device bodies ----------------

__device__ inline void gemm_body(int bid, int tid,
                                 const float* __restrict__ Xf,
                                 const __half* __restrict__ WhT,
                                 __half* __restrict__ Hh, int n,
                                 _Float16* wlds) {
#pragma unroll
    for (int q = 0; q < 8; ++q) {
        int idx = tid + q * 256;        // 0..2047, each = 8 halves
        int row = idx >> 4;
        int col8 = (idx & 15) * 8;
        const uint2* gsrc = (const uint2*)(WhT + row * 128 + col8);
        uint2 a = gsrc[0];
        uint2 b = gsrc[1];
        uint2* ldst = (uint2*)(wlds + row * WP + col8);
        ldst[0] = a;
        ldst[1] = b;
    }
    __syncthreads();

    const int wave = tid >> 6;
    const int lane = tid & 63;
    const int m = lane & 15;
    const int quad = lane >> 4;

    const int node = bid * 64 + wave * 16 + m;
    const int node_ld = node < n ? node : (n - 1);

    half8 bfr[4];
#pragma unroll
    for (int k = 0; k < 4; ++k) {
        const float4* p = (const float4*)(Xf + (size_t)node_ld * 128 + k * 32 + quad * 8);
        float4 lo = p[0];
        float4 hi = p[1];
        half8 h;
        h[0] = (_Float16)lo.x; h[1] = (_Float16)lo.y;
        h[2] = (_Float16)lo.z; h[3] = (_Float16)lo.w;
        h[4] = (_Float16)hi.x; h[5] = (_Float16)hi.y;
        h[6] = (_Float16)hi.z; h[7] = (_Float16)hi.w;
        bfr[k] = h;
    }

    floatx4 acc[8];
#pragma unroll
    for (int f = 0; f < 8; ++f) acc[f] = (floatx4){0.f, 0.f, 0.f, 0.f};

#pragma unroll
    for (int f = 0; f < 8; ++f) {
#pragma unroll
        for (int k = 0; k < 4; ++k) {
            half8 a = *(const half8*)(wlds + (f * 16 + m) * WP + k * 32 + quad * 8);
            acc[f] = __builtin_amdgcn_mfma_f32_16x16x32_f16(a, bfr[k], acc[f], 0, 0, 0);
        }
    }

    if (node < n) {
#pragma unroll
        for (int f = 0; f < 8; ++f) {
            __half2 p0 = __floats2half2_rn(acc[f][0], acc[f][1]);
            __half2 p1 = __floats2half2_rn(acc[f][2], acc[f][3]);
            uint2 pk;
            pk.x = *(unsigned int*)&p0;
            pk.y = *(unsigned int*)&p1;
            *(uint2*)(Hh + (size_t)node * 128 + f * 16 + quad * 4) = pk;
        }
    }
}

// Rank-free fill: slot = row_ptr[d] + base8[c*n+d] + cursor8[c*n+d]++.
// cursor8 zeroed by the same memset as deg8. Any arrival order gives a
// unique slot within the (d,c) segment.
__device__ inline void fill_body(int i,
                                 const int* __restrict__ src,
                                 const int* __restrict__ dst,
                                 int* __restrict__ cursor8,
                                 const int* __restrict__ row_ptr,
                                 const int* __restrict__ base8,
                                 const float* __restrict__ dinv,
                                 int2* __restrict__ recs, int e, int n) {
    if (i < e) {
        int d = dst[i];
        int s = src[i];
        int c = s >> 13;        // src band -- must match count_kernel
        int r = atomicAdd(&cursor8[c * n + d], 1);
        int pos = row_ptr[d] + base8[c * n + d] + r;
        int2 rec;
        rec.x = s;
        rec.y = __float_as_int(dinv[s] * dinv[d]);
        recs[pos] = rec;
    }
}

// ---------------- fused layer-0 GEMM + CSR fill (measured win: overlap) ----------------

__global__ __launch_bounds__(256) void gemmfill_kernel(const float* __restrict__ Xf,
                                                       const __half* __restrict__ WhT,
                                                       __half* __restrict__ Hh, int n, int nbg,
                                                       const int* __restrict__ src,
                                                       const int* __restrict__ dst,
                                                       int* __restrict__ cursor8,
                                                       const int* __restrict__ row_ptr,
                                                       const int* __restrict__ base8,
                                                       const float* __restrict__ dinv,
                                                       int2* __restrict__ recs, int e) {
    __shared__ _Float16 wlds[128 * WP];
    int bid = blockIdx.x;
    int tid = threadIdx.x;
    if (bid < nbg) {
        gemm_body(bid, tid, Xf, WhT, Hh, n, wlds);
    } else {
        fill_body((bid - nbg) * 256 + tid, src, dst, cursor8, row_ptr, base8, dinv, recs, e, n);
    }
}

// ---------------- Aggregation core (R19/R22: one node per quarter-wave) ----------------

__device__ inline void unpack8(uint4 u, float* f) {
    union { unsigned int x; __half2 h; } a, b, c, d;
    a.x = u.x; b.x = u.y; c.x = u.z; d.x = u.w;
    float2 f0 = __half22float2(a.h);
    float2 f1 = __half22float2(b.h);
    float2 f2 = __half22float2(c.h);
    float2 f3 = __half22float2(d.h);
    f[0] = f0.x; f[1] = f0.y; f[2] = f1.x; f[3] = f1.y;
    f[4] = f2.x; f[5] = f2.y; f[6] = f3.x; f[7] = f3.y;
}

// Quarter-wave walks node v's full edge list, ABI edges in flight.
// Lane fl holds features [fl*8, fl*8+8). acc = complete row sum (no reduce).
__device__ inline void agg_row_q(int v, int fl,
                                 const uint4* __restrict__ H16,
                                 const int2* __restrict__ recs,
                                 const int* __restrict__ row_ptr,
                                 const float* __restrict__ dinv,
                                 float* acc) {
    {
        float di = dinv[v];
        float selfc = di * di;
        uint4 hv = H16[(size_t)v * 16 + fl];
        float f[8]; unpack8(hv, f);
#pragma unroll
        for (int t = 0; t < 8; ++t) acc[t] = f[t] * selfc;
    }

    int e0 = row_ptr[v];
    int e1 = row_ptr[v + 1];
    int e = e0;
    for (; e + ABI <= e1; e += ABI) {
        int2 r[ABI]; uint4 hu[ABI];
#pragma unroll
        for (int j = 0; j < ABI; ++j) r[j] = recs[e + j];      // quarter-uniform, HW broadcast
#pragma unroll
        for (int j = 0; j < ABI; ++j) hu[j] = H16[(size_t)r[j].x * 16 + fl];
#pragma unroll
        for (int j = 0; j < ABI; ++j) {
            float c = __int_as_float(r[j].y);
            float f[8]; unpack8(hu[j], f);
#pragma unroll
            for (int t = 0; t < 8; ++t) acc[t] = fmaf(f[t], c, acc[t]);
        }
    }
    if (e < e1) {
        int2 r[ABI]; uint4 hu[ABI]; bool act[ABI];
#pragma unroll
        for (int j = 0; j < ABI; ++j) {
            act[j] = (e + j) < e1;
            if (act[j]) r[j] = recs[e + j];
        }
#pragma unroll
        for (int j = 0; j < ABI; ++j) {
            if (act[j]) hu[j] = H16[(size_t)r[j].x * 16 + fl];
        }
#pragma unroll
        for (int j = 0; j < ABI; ++j) {
            if (act[j]) {
                float c = __int_as_float(r[j].y);
                float f[8]; unpack8(hu[j], f);
#pragma unroll
                for (int t = 0; t < 8; ++t) acc[t] = fmaf(f[t], c, acc[t]);
            }
        }
    }
}

// Standalone agg (layer 1 -> fp32 out). 4 waves x 4 nodes = 16 nodes/block.
__global__ __launch_bounds__(256, 4) void agg_kernel(const __half* __restrict__ H,
                                                     const int2* __restrict__ recs,
                                                     const int* __restrict__ row_ptr,
                                                     const float* __restrict__ dinv,
                                                     const float* __restrict__ bias,
                                                     float* __restrict__ YF, int n) {
    int wave = threadIdx.x >> 6;
    int lane = threadIdx.x & 63;
    int qw = lane >> 4;
    int fl = lane & 15;
    int v = blockIdx.x * 16 + wave * 4 + qw;
    if (v >= n) return;

    const uint4* H16 = (const uint4*)H;
    float acc[8];
    agg_row_q(v, fl, H16, recs, row_ptr, dinv, acc);

    const float4* B4 = (const float4*)bias;
    float4 b0 = B4[fl * 2];
    float4 b1 = B4[fl * 2 + 1];
    float4* Y4 = (float4*)YF;
    Y4[(size_t)v * 32 + fl * 2] = make_float4(
        fmaxf(acc[0] + b0.x, 0.f), fmaxf(acc[1] + b0.y, 0.f),
        fmaxf(acc[2] + b0.z, 0.f), fmaxf(acc[3] + b0.w, 0.f));
    Y4[(size_t)v * 32 + fl * 2 + 1] = make_float4(
        fmaxf(acc[4] + b1.x, 0.f), fmaxf(acc[5] + b1.y, 0.f),
        fmaxf(acc[6] + b1.z, 0.f), fmaxf(acc[7] + b1.w, 0.f));
}

// ---------------- fused agg(layer0) + GEMM(layer1), 32-node tile ----------------
// Block g: 8 waves x 4 nodes (one per quarter-wave) -> LDS y-tile, block-local
// barrier, then 32x128 @ W2 MFMA tile. Output -> H2 (NOT H: other blocks
// still gather from H).
__global__ __launch_bounds__(512, 4) void aggemm_kernel(
    const __half* __restrict__ H,
    const int2* __restrict__ recs,
    const int* __restrict__ row_ptr,
    const float* __restrict__ dinv,
    const float* __restrict__ bias,       // layer-0 bias
    const __half* __restrict__ WhT2,      // layer-1 W^T
    __half* __restrict__ H2, int n) {
    __shared__ _Float16 yt[AGT * YP];
    const int tid = threadIdx.x;
    const int wave = tid >> 6;
    const int lane = tid & 63;
    const int qw = lane >> 4;
    const int fl = lane & 15;
    const int g = blockIdx.x;
    const uint4* H16 = (const uint4*)H;

    // ---- phase 1: one node per quarter-wave into y-tile ----
    {
        const float4* B4 = (const float4*)bias;
        float4 b0 = B4[fl * 2];
        float4 b1 = B4[fl * 2 + 1];
        int r = wave * 4 + qw;           // local row 0..31
        int v = g * AGT + r;
        if (v < n) {
            float acc[8];
            agg_row_q(v, fl, H16, recs, row_ptr, dinv, acc);
            __half2 p0 = __floats2half2_rn(fmaxf(acc[0] + b0.x, 0.f), fmaxf(acc[1] + b0.y, 0.f));
            __half2 p1 = __floats2half2_rn(fmaxf(acc[2] + b0.z, 0.f), fmaxf(acc[3] + b0.w, 0.f));
            __half2 p2 = __floats2half2_rn(fmaxf(acc[4] + b1.x, 0.f), fmaxf(acc[5] + b1.y, 0.f));
            __half2 p3 = __floats2half2_rn(fmaxf(acc[6] + b1.z, 0.f), fmaxf(acc[7] + b1.w, 0.f));
            uint4 pk;
            pk.x = *(unsigned int*)&p0;
            pk.y = *(unsigned int*)&p1;
            pk.z = *(unsigned int*)&p2;
            pk.w = *(unsigned int*)&p3;
            *(uint4*)&yt[r * YP + fl * 8] = pk;
        } else {
            uint4 z = make_uint4(0, 0, 0, 0);
            *(uint4*)&yt[r * YP + fl * 8] = z;
        }
    }
    __syncthreads();

    // ---- phase 2: GEMM 32x128 @ W2 -> H2 ----
    const int mg = wave & 1;             // node-group (16 nodes)
    const int fh = wave >> 1;            // 2 f-blocks per wave
    const int node = g * AGT + mg * 16 + fl;

    half8 bfr[4];
#pragma unroll
    for (int k = 0; k < 4; ++k)
        bfr[k] = *(const half8*)&yt[(mg * 16 + fl) * YP + k * 32 + qw * 8];

#pragma unroll
    for (int fb = 0; fb < 2; ++fb) {
        int f = fh * 2 + fb;
        floatx4 a4 = (floatx4){0.f, 0.f, 0.f, 0.f};
#pragma unroll
        for (int k = 0; k < 4; ++k) {
            half8 a = *(const half8*)(WhT2 + ((f * 16 + fl) * 128 + k * 32 + qw * 8));
            a4 = __builtin_amdgcn_mfma_f32_16x16x32_f16(a, bfr[k], a4, 0, 0, 0);
        }
        if (node < n) {
            __half2 p0 = __floats2half2_rn(a4[0], a4[1]);
            __half2 p1 = __floats2half2_rn(a4[2], a4[3]);
            uint2 pk;
            pk.x = *(unsigned int*)&p0;
            pk.y = *(unsigned int*)&p1;
            *(uint2*)(H2 + (size_t)node * 128 + f * 16 + qw * 4) = pk;
        }
    }
}

// ---------------- launch ----------------

extern "C" void kernel_launch(void* const* d_in, const int* in_sizes, int n_in,
                              void* d_out, int out_size, void* d_ws, size_t ws_size,
                              hipStream_t stream) {
    const float* x = (const float*)d_in[0];
    const int* ei = (const int*)d_in[1];
    const float* W = (const float*)d_in[2];
    const float* b = (const float*)d_in[3];
    float* out = (float*)d_out;

    const int N = in_sizes[0] / D;       // 50000
    const int E = in_sizes[1] / 2;       // 800000

    const int* src = ei;
    const int* dst = ei + E;

    int* wsi = (int*)d_ws;
    float* wsf = (float*)d_ws;
    const size_t o_deg8 = 0;                 // 8*N ints (memset 0)
    const size_t o_cur8 = o_deg8 + 400000;   // 8*N ints (memset 0, fill cursors)
    const size_t o_degT = o_cur8 + 400000;   // N ints
    const size_t o_dinv = o_degT + 50000;    // N floats
    const size_t o_rp   = o_dinv + 50000;    // N+1 ints (pad 50016)
    const size_t o_part = o_rp + 50016;      // 256
    const size_t o_b8   = o_part + 256;      // 8*N ints
    const size_t o_rec  = o_b8 + 400000;     // E int2
    const size_t o_h    = o_rec + 1600000;   // N*128 halves = 3.2M words (16B-aligned)
    const size_t o_wht  = o_h + 3200000;     // 2*128*128 halves = 16384 words
    const size_t o_h2   = o_wht + 16384;     // N*128 halves (layer-1 GEMM out)

    int* deg8    = wsi + o_deg8;
    int* cursor8 = wsi + o_cur8;
    int* degT    = wsi + o_degT;
    float* dinv  = wsf + o_dinv;
    int* row_ptr = wsi + o_rp;
    int* partial = wsi + o_part;
    int* base8   = wsi + o_b8;
    int2* recs   = (int2*)(wsi + o_rec);
    __half* h    = (__half*)(wsi + o_h);
    __half* wht  = (__half*)(wsi + o_wht);
    __half* h2   = (__half*)(wsi + o_h2);

    const int nb_e = (E + 255) / 256;           // 3125
    const int nb_s = (N + 255) / 256;           // 196
    const int nb_g = (N + 63) / 64;             // 782
    const int nb_ag = (N + AGT - 1) / AGT;      // 1563
    const int nb_a = (N + 15) / 16;             // 3125 (16 nodes per 256-thr block)

    // zero deg8 + cursor8 in one memset
    hipMemsetAsync(deg8, 0, (size_t)16 * 50000 * sizeof(int), stream);
    count_kernel<<<nb_e, 256, 0, stream>>>(src, dst, deg8, E, N);
    scanA_cvtw_kernel<<<nb_s + 128, 256, 0, stream>>>(deg8, degT, base8, partial,
                                                      N, nb_s, W, wht);
    scanC2_kernel<<<nb_s, 256, 0, stream>>>(degT, partial, row_ptr, dinv, N);
    // fused: layer-0 GEMM (blocks [0,nb_g)) + CSR fill (blocks [nb_g,...))
    gemmfill_kernel<<<nb_g + nb_e, 256, 0, stream>>>(x, wht, h, N, nb_g,
                                                     src, dst, cursor8, row_ptr, base8,
                                                     dinv, recs, E);
    // fused: agg layer-0 + GEMM layer-1 (block-local, no grid sync needed)
    aggemm_kernel<<<nb_ag, 512, 0, stream>>>(h, recs, row_ptr, dinv, b,
                                             wht + 16384, h2, N);
    agg_kernel<<<nb_a, 256, 0, stream>>>(h2, recs, row_ptr, dinv, b + D, out, N);
}

// Round 11
// 217.007 us; speedup vs baseline: 1.3425x; 1.1088x over previous
//
#include <hip/hip_runtime.h>
#include <hip/hip_fp16.h>

// StaticGNN: 2-layer GCN. N=50000, E=800000, D=128, fp32 in/out.
// out = relu( D^{-1/2}(A+I)D^{-1/2} (X W_l) + b_l ), x2.
// H fp16; CSR recs int2{src,coef}.
// R25 = REVERT TO MEASURED BEST (R19, 219.2us). Evidence ledger:
//  - agg core across 8 structures (R17-R24): 68/58/47/57/52/47/82/50 us.
//    Best = quarter-per-node, ABI=8 predicated, LB(512,4)/(256,4).
//  - Wall: FETCH pinned ~82MB, L2-miss service 1.7-2.0 TB/s, insensitive to
//    occupancy (18-61%), batch depth (8/12/16), src-banding, band-sweep.
//  - Closed levers: fp8 H (absmax budget), scatter-add (16x write scatter),
//    grid-sync fusion (~70us/barrier, R16), band sweep (kills MLP, R23),
//    always-issue batches (+50% gathers, R20), rank-free fill (R24, slower).
// Floor arithmetic: 2 x 47us agg (205MB/pass @ ~4.4TB/s random-gather
// service) + 25us gemmfill + ~25us prep + dispatch gaps ~= 215-225us.
// 7 dispatches: memset, count, scanA+cvtw, scanC2, gemmfill, aggemm, agg2.

#define D 128
#define WP 136   // LDS pitch (halves) for W^T tile
#define YP 136   // LDS pitch (halves) for y-tile in aggemm
#define ABI 8    // edges in flight per quarter-wave (gather pipeline depth)
#define AGT 32   // aggemm node tile (8 waves x 4 nodes, 1 node per quarter)
#define NB_SCAN 196     // ceil(50000/256)

typedef _Float16 half8 __attribute__((ext_vector_type(8)));
typedef float floatx4 __attribute__((ext_vector_type(4)));

// ---------------- setup kernels ----------------

// deg8[8][n] zeroed by memset. Copy c = blockIdx&7. rank = within-copy rank.
__global__ void count_kernel(const int* __restrict__ dst, int* deg8,
                             int* __restrict__ rank, int e, int n) {
    int i = blockIdx.x * blockDim.x + threadIdx.x;
    int c = (blockIdx.x & 7) * n;
    if (i < e) rank[i] = atomicAdd(&deg8[c + dst[i]], 1);
}

// scanA: per-node total degree + per-copy exclusive bases; block sums -> partial.
// cvtw (W fp32 -> W^T fp16) fused as independent block-range tail.
__global__ __launch_bounds__(256) void scanA_cvtw_kernel(const int* __restrict__ deg8,
                                                         int* __restrict__ degT,
                                                         int* __restrict__ base8,
                                                         int* __restrict__ partial,
                                                         int n, int nbs,
                                                         const float* __restrict__ W,
                                                         __half* __restrict__ WhT) {
    __shared__ int red[4];
    int tid = threadIdx.x;
    int bid = blockIdx.x;
    if (bid < nbs) {
        int i = bid * 256 + tid;
        int tot = 0;
        if (i < n) {
            int run = 0;
#pragma unroll
            for (int c = 0; c < 8; ++c) {
                base8[c * n + i] = run;
                run += deg8[c * n + i];
            }
            degT[i] = run;
            tot = run;
        }
        for (int off = 32; off > 0; off >>= 1) tot += __shfl_down(tot, off, 64);
        if ((tid & 63) == 0) red[tid >> 6] = tot;
        __syncthreads();
        if (tid == 0) partial[bid] = red[0] + red[1] + red[2] + red[3];
    } else {
        // W[l][k][f] -> WhT[l][f][k]; 128 blocks x 256 threads = 32768 elems
        int id = (bid - nbs) * 256 + tid;
        int l = id >> 14;
        int rem = id & 16383;
        int f = rem >> 7;
        int k = rem & 127;
        WhT[id] = __float2half(W[l * 16384 + k * 128 + f]);
    }
}

// scanC2: scanB folded in -- every block locally scans the 196 partials,
// then does its in-block node scan. Writes row_ptr + dinv.
__global__ __launch_bounds__(256) void scanC2_kernel(const int* __restrict__ degT,
                                                     const int* __restrict__ partial,
                                                     int* __restrict__ row_ptr,
                                                     float* __restrict__ dinv, int n) {
    __shared__ int sc[256];
    __shared__ int scb[256];
    int tid = threadIdx.x;
    int bid = blockIdx.x;
    int p = (tid < NB_SCAN) ? partial[tid] : 0;
    scb[tid] = p;
    __syncthreads();
    for (int off = 1; off < 256; off <<= 1) {
        int v = (tid >= off) ? scb[tid - off] : 0;
        __syncthreads();
        scb[tid] += v;
        __syncthreads();
    }
    int i = bid * 256 + tid;
    int c = (i < n) ? degT[i] : 0;
    sc[tid] = c;
    __syncthreads();
    for (int off = 1; off < 256; off <<= 1) {
        int v = (tid >= off) ? sc[tid - off] : 0;
        __syncthreads();
        sc[tid] += v;
        __syncthreads();
    }
    if (i < n) {
        int base = ((bid == 0) ? 0 : scb[bid - 1]) + sc[tid] - c;
        row_ptr[i] = base;
        dinv[i] = rsqrtf((float)(c + 1));
    }
    if (bid == 0 && tid == 0) row_ptr[n] = scb[NB_SCAN - 1];
}

// ---------------- shared device bodies ----------------

__device__ inline void gemm_body(int bid, int tid,
                                 const float* __restrict__ Xf,
                                 const __half* __restrict__ WhT,
                                 __half* __restrict__ Hh, int n,
                                 _Float16* wlds) {
#pragma unroll
    for (int q = 0; q < 8; ++q) {
        int idx = tid + q * 256;        // 0..2047, each = 8 halves
        int row = idx >> 4;
        int col8 = (idx & 15) * 8;
        const uint2* gsrc = (const uint2*)(WhT + row * 128 + col8);
        uint2 a = gsrc[0];
        uint2 b = gsrc[1];
        uint2* ldst = (uint2*)(wlds + row * WP + col8);
        ldst[0] = a;
        ldst[1] = b;
    }
    __syncthreads();

    const int wave = tid >> 6;
    const int lane = tid & 63;
    const int m = lane & 15;
    const int quad = lane >> 4;

    const int node = bid * 64 + wave * 16 + m;
    const int node_ld = node < n ? node : (n - 1);

    half8 bfr[4];
#pragma unroll
    for (int k = 0; k < 4; ++k) {
        const float4* p = (const float4*)(Xf + (size_t)node_ld * 128 + k * 32 + quad * 8);
        float4 lo = p[0];
        float4 hi = p[1];
        half8 h;
        h[0] = (_Float16)lo.x; h[1] = (_Float16)lo.y;
        h[2] = (_Float16)lo.z; h[3] = (_Float16)lo.w;
        h[4] = (_Float16)hi.x; h[5] = (_Float16)hi.y;
        h[6] = (_Float16)hi.z; h[7] = (_Float16)hi.w;
        bfr[k] = h;
    }

    floatx4 acc[8];
#pragma unroll
    for (int f = 0; f < 8; ++f) acc[f] = (floatx4){0.f, 0.f, 0.f, 0.f};

#pragma unroll
    for (int f = 0; f < 8; ++f) {
#pragma unroll
        for (int k = 0; k < 4; ++k) {
            half8 a = *(const half8*)(wlds + (f * 16 + m) * WP + k * 32 + quad * 8);
            acc[f] = __builtin_amdgcn_mfma_f32_16x16x32_f16(a, bfr[k], acc[f], 0, 0, 0);
        }
    }

    if (node < n) {
#pragma unroll
        for (int f = 0; f < 8; ++f) {
            __half2 p0 = __floats2half2_rn(acc[f][0], acc[f][1]);
            __half2 p1 = __floats2half2_rn(acc[f][2], acc[f][3]);
            uint2 pk;
            pk.x = *(unsigned int*)&p0;
            pk.y = *(unsigned int*)&p1;
            *(uint2*)(Hh + (size_t)node * 128 + f * 16 + quad * 4) = pk;
        }
    }
}

__device__ inline void fill_body(int i,
                                 const int* __restrict__ src,
                                 const int* __restrict__ dst,
                                 const int* __restrict__ rank,
                                 const int* __restrict__ row_ptr,
                                 const int* __restrict__ base8,
                                 const float* __restrict__ dinv,
                                 int2* __restrict__ recs, int e, int n) {
    if (i < e) {
        int d = dst[i];
        int s = src[i];
        int c = (i >> 8) & 7;   // copy used by count (blockIdx&7, blockDim=256)
        int pos = row_ptr[d] + base8[c * n + d] + rank[i];
        int2 rec;
        rec.x = s;
        rec.y = __float_as_int(dinv[s] * dinv[d]);
        recs[pos] = rec;
    }
}

// ---------------- fused layer-0 GEMM + CSR fill (measured win: overlap) ----------------

__global__ __launch_bounds__(256) void gemmfill_kernel(const float* __restrict__ Xf,
                                                       const __half* __restrict__ WhT,
                                                       __half* __restrict__ Hh, int n, int nbg,
                                                       const int* __restrict__ src,
                                                       const int* __restrict__ dst,
                                                       const int* __restrict__ rank,
                                                       const int* __restrict__ row_ptr,
                                                       const int* __restrict__ base8,
                                                       const float* __restrict__ dinv,
                                                       int2* __restrict__ recs, int e) {
    __shared__ _Float16 wlds[128 * WP];
    int bid = blockIdx.x;
    int tid = threadIdx.x;
    if (bid < nbg) {
        gemm_body(bid, tid, Xf, WhT, Hh, n, wlds);
    } else {
        fill_body((bid - nbg) * 256 + tid, src, dst, rank, row_ptr, base8, dinv, recs, e, n);
    }
}

// ---------------- Aggregation core (R19: one node per quarter-wave) ----------------

__device__ inline void unpack8(uint4 u, float* f) {
    union { unsigned int x; __half2 h; } a, b, c, d;
    a.x = u.x; b.x = u.y; c.x = u.z; d.x = u.w;
    float2 f0 = __half22float2(a.h);
    float2 f1 = __half22float2(b.h);
    float2 f2 = __half22float2(c.h);
    float2 f3 = __half22float2(d.h);
    f[0] = f0.x; f[1] = f0.y; f[2] = f1.x; f[3] = f1.y;
    f[4] = f2.x; f[5] = f2.y; f[6] = f3.x; f[7] = f3.y;
}

// Quarter-wave walks node v's full edge list, ABI edges in flight.
// Lane fl holds features [fl*8, fl*8+8). acc = complete row sum (no reduce).
__device__ inline void agg_row_q(int v, int fl,
                                 const uint4* __restrict__ H16,
                                 const int2* __restrict__ recs,
                                 const int* __restrict__ row_ptr,
                                 const float* __restrict__ dinv,
                                 float* acc) {
    {
        float di = dinv[v];
        float selfc = di * di;
        uint4 hv = H16[(size_t)v * 16 + fl];
        float f[8]; unpack8(hv, f);
#pragma unroll
        for (int t = 0; t < 8; ++t) acc[t] = f[t] * selfc;
    }

    int e0 = row_ptr[v];
    int e1 = row_ptr[v + 1];
    int e = e0;
    for (; e + ABI <= e1; e += ABI) {
        int2 r[ABI]; uint4 hu[ABI];
#pragma unroll
        for (int j = 0; j < ABI; ++j) r[j] = recs[e + j];      // quarter-uniform, HW broadcast
#pragma unroll
        for (int j = 0; j < ABI; ++j) hu[j] = H16[(size_t)r[j].x * 16 + fl];
#pragma unroll
        for (int j = 0; j < ABI; ++j) {
            float c = __int_as_float(r[j].y);
            float f[8]; unpack8(hu[j], f);
#pragma unroll
            for (int t = 0; t < 8; ++t) acc[t] = fmaf(f[t], c, acc[t]);
        }
    }
    if (e < e1) {
        int2 r[ABI]; uint4 hu[ABI]; bool act[ABI];
#pragma unroll
        for (int j = 0; j < ABI; ++j) {
            act[j] = (e + j) < e1;
            if (act[j]) r[j] = recs[e + j];
        }
#pragma unroll
        for (int j = 0; j < ABI; ++j) {
            if (act[j]) hu[j] = H16[(size_t)r[j].x * 16 + fl];
        }
#pragma unroll
        for (int j = 0; j < ABI; ++j) {
            if (act[j]) {
                float c = __int_as_float(r[j].y);
                float f[8]; unpack8(hu[j], f);
#pragma unroll
                for (int t = 0; t < 8; ++t) acc[t] = fmaf(f[t], c, acc[t]);
            }
        }
    }
}

// Standalone agg (layer 1 -> fp32 out). 4 waves x 4 nodes = 16 nodes/block.
__global__ __launch_bounds__(256, 4) void agg_kernel(const __half* __restrict__ H,
                                                     const int2* __restrict__ recs,
                                                     const int* __restrict__ row_ptr,
                                                     const float* __restrict__ dinv,
                                                     const float* __restrict__ bias,
                                                     float* __restrict__ YF, int n) {
    int wave = threadIdx.x >> 6;
    int lane = threadIdx.x & 63;
    int qw = lane >> 4;
    int fl = lane & 15;
    int v = blockIdx.x * 16 + wave * 4 + qw;
    if (v >= n) return;

    const uint4* H16 = (const uint4*)H;
    float acc[8];
    agg_row_q(v, fl, H16, recs, row_ptr, dinv, acc);

    const float4* B4 = (const float4*)bias;
    float4 b0 = B4[fl * 2];
    float4 b1 = B4[fl * 2 + 1];
    float4* Y4 = (float4*)YF;
    Y4[(size_t)v * 32 + fl * 2] = make_float4(
        fmaxf(acc[0] + b0.x, 0.f), fmaxf(acc[1] + b0.y, 0.f),
        fmaxf(acc[2] + b0.z, 0.f), fmaxf(acc[3] + b0.w, 0.f));
    Y4[(size_t)v * 32 + fl * 2 + 1] = make_float4(
        fmaxf(acc[4] + b1.x, 0.f), fmaxf(acc[5] + b1.y, 0.f),
        fmaxf(acc[6] + b1.z, 0.f), fmaxf(acc[7] + b1.w, 0.f));
}

// ---------------- fused agg(layer0) + GEMM(layer1), 32-node tile ----------------
// Block g: 8 waves x 4 nodes (one per quarter-wave) -> LDS y-tile, block-local
// barrier, then 32x128 @ W2 MFMA tile. Output -> H2 (NOT H: other blocks
// still gather from H).
__global__ __launch_bounds__(512, 4) void aggemm_kernel(
    const __half* __restrict__ H,
    const int2* __restrict__ recs,
    const int* __restrict__ row_ptr,
    const float* __restrict__ dinv,
    const float* __restrict__ bias,       // layer-0 bias
    const __half* __restrict__ WhT2,      // layer-1 W^T
    __half* __restrict__ H2, int n) {
    __shared__ _Float16 yt[AGT * YP];
    const int tid = threadIdx.x;
    const int wave = tid >> 6;
    const int lane = tid & 63;
    const int qw = lane >> 4;
    const int fl = lane & 15;
    const int g = blockIdx.x;
    const uint4* H16 = (const uint4*)H;

    // ---- phase 1: one node per quarter-wave into y-tile ----
    {
        const float4* B4 = (const float4*)bias;
        float4 b0 = B4[fl * 2];
        float4 b1 = B4[fl * 2 + 1];
        int r = wave * 4 + qw;           // local row 0..31
        int v = g * AGT + r;
        if (v < n) {
            float acc[8];
            agg_row_q(v, fl, H16, recs, row_ptr, dinv, acc);
            __half2 p0 = __floats2half2_rn(fmaxf(acc[0] + b0.x, 0.f), fmaxf(acc[1] + b0.y, 0.f));
            __half2 p1 = __floats2half2_rn(fmaxf(acc[2] + b0.z, 0.f), fmaxf(acc[3] + b0.w, 0.f));
            __half2 p2 = __floats2half2_rn(fmaxf(acc[4] + b1.x, 0.f), fmaxf(acc[5] + b1.y, 0.f));
            __half2 p3 = __floats2half2_rn(fmaxf(acc[6] + b1.z, 0.f), fmaxf(acc[7] + b1.w, 0.f));
            uint4 pk;
            pk.x = *(unsigned int*)&p0;
            pk.y = *(unsigned int*)&p1;
            pk.z = *(unsigned int*)&p2;
            pk.w = *(unsigned int*)&p3;
            *(uint4*)&yt[r * YP + fl * 8] = pk;
        } else {
            uint4 z = make_uint4(0, 0, 0, 0);
            *(uint4*)&yt[r * YP + fl * 8] = z;
        }
    }
    __syncthreads();

    // ---- phase 2: GEMM 32x128 @ W2 -> H2 ----
    const int mg = wave & 1;             // node-group (16 nodes)
    const int fh = wave >> 1;            // 2 f-blocks per wave
    const int node = g * AGT + mg * 16 + fl;

    half8 bfr[4];
#pragma unroll
    for (int k = 0; k < 4; ++k)
        bfr[k] = *(const half8*)&yt[(mg * 16 + fl) * YP + k * 32 + qw * 8];

#pragma unroll
    for (int fb = 0; fb < 2; ++fb) {
        int f = fh * 2 + fb;
        floatx4 a4 = (floatx4){0.f, 0.f, 0.f, 0.f};
#pragma unroll
        for (int k = 0; k < 4; ++k) {
            half8 a = *(const half8*)(WhT2 + ((f * 16 + fl) * 128 + k * 32 + qw * 8));
            a4 = __builtin_amdgcn_mfma_f32_16x16x32_f16(a, bfr[k], a4, 0, 0, 0);
        }
        if (node < n) {
            __half2 p0 = __floats2half2_rn(a4[0], a4[1]);
            __half2 p1 = __floats2half2_rn(a4[2], a4[3]);
            uint2 pk;
            pk.x = *(unsigned int*)&p0;
            pk.y = *(unsigned int*)&p1;
            *(uint2*)(H2 + (size_t)node * 128 + f * 16 + qw * 4) = pk;
        }
    }
}

// ---------------- launch ----------------

extern "C" void kernel_launch(void* const* d_in, const int* in_sizes, int n_in,
                              void* d_out, int out_size, void* d_ws, size_t ws_size,
                              hipStream_t stream) {
    const float* x = (const float*)d_in[0];
    const int* ei = (const int*)d_in[1];
    const float* W = (const float*)d_in[2];
    const float* b = (const float*)d_in[3];
    float* out = (float*)d_out;

    const int N = in_sizes[0] / D;       // 50000
    const int E = in_sizes[1] / 2;       // 800000

    const int* src = ei;
    const int* dst = ei + E;

    int* wsi = (int*)d_ws;
    float* wsf = (float*)d_ws;
    const size_t o_deg8 = 0;                 // 8*N ints (memset 0)
    const size_t o_degT = o_deg8 + 400000;   // N ints
    const size_t o_dinv = o_degT + 50000;    // N floats
    const size_t o_rp   = o_dinv + 50000;    // N+1 ints (pad 50016)
    const size_t o_part = o_rp + 50016;      // 256
    const size_t o_boff = o_part + 256;      // 256 (unused, layout kept)
    const size_t o_b8   = o_boff + 256;      // 8*N ints
    const size_t o_rank = o_b8 + 400000;     // E ints
    const size_t o_rec  = o_rank + 800000;   // E int2 (region 16B-aligned)
    const size_t o_h    = o_rec + 1600000;   // N*128 halves = 3.2M words
    const size_t o_wht  = o_h + 3200000;     // 2*128*128 halves = 16384 words
    const size_t o_h2   = o_wht + 16384;     // N*128 halves (layer-1 GEMM out)

    int* deg8    = wsi + o_deg8;
    int* degT    = wsi + o_degT;
    float* dinv  = wsf + o_dinv;
    int* row_ptr = wsi + o_rp;
    int* partial = wsi + o_part;
    int* base8   = wsi + o_b8;
    int* rank    = wsi + o_rank;
    int2* recs   = (int2*)(wsi + o_rec);
    __half* h    = (__half*)(wsi + o_h);
    __half* wht  = (__half*)(wsi + o_wht);
    __half* h2   = (__half*)(wsi + o_h2);

    const int nb_e = (E + 255) / 256;           // 3125
    const int nb_s = (N + 255) / 256;           // 196
    const int nb_g = (N + 63) / 64;             // 782
    const int nb_ag = (N + AGT - 1) / AGT;      // 1563
    const int nb_a = (N + 15) / 16;             // 3125 (16 nodes per 256-thr block)

    hipMemsetAsync(deg8, 0, (size_t)8 * 50000 * sizeof(int), stream);
    count_kernel<<<nb_e, 256, 0, stream>>>(dst, deg8, rank, E, N);
    scanA_cvtw_kernel<<<nb_s + 128, 256, 0, stream>>>(deg8, degT, base8, partial,
                                                      N, nb_s, W, wht);
    scanC2_kernel<<<nb_s, 256, 0, stream>>>(degT, partial, row_ptr, dinv, N);
    // fused: layer-0 GEMM (blocks [0,nb_g)) + CSR fill (blocks [nb_g,...))
    gemmfill_kernel<<<nb_g + nb_e, 256, 0, stream>>>(x, wht, h, N, nb_g,
                                                     src, dst, rank, row_ptr, base8,
                                                     dinv, recs, E);
    // fused: agg layer-0 + GEMM layer-1 (block-local, no grid sync needed)
    aggemm_kernel<<<nb_ag, 512, 0, stream>>>(h, recs, row_ptr, dinv, b,
                                             wht + 16384, h2, N);
    agg_kernel<<<nb_a, 256, 0, stream>>>(h2, recs, row_ptr, dinv, b + D, out, N);
}